// Round 6
// baseline (178.126 us; speedup 1.0000x reference)
//
#include <hip/hip_runtime.h>
#include <hip/hip_fp16.h>

// OTK (optimal-transport kernel attention) for MI355X.
// Pipeline:
//   k0: xT[b][d][n] = fp16(x)            (transpose for k3 B-operand)
//   k1: E[b][h][n][m] = exp(-10*C*pf)    (fp16 MFMA GEMM + fused epilogue)
//   k2: exp-domain Sinkhorn, E register-resident, 512 thr/block (4 rows/thr)
//   k3: out[b][m*4+h][d] = Pt @ x        (fp16 MFMA GEMM)
// Identity: lse_m(K+u+v) = u + lse_m(K+v)  =>  plain Sinkhorn on E=exp(K).
//
// Lessons: r2/r3 — compiler remats loop-invariant global loads instead of
// keeping 128 VGPRs live. r4 — pinning runtime-indexed ARRAY ELEMENTS blocks
// SROA (rule #20): pin was a no-op. r5 — "+v" on uint4 = 128-bit tied
// indirect asm operand: backend rejects it. This round: explode each uint4
// into 4 NAMED unsigned-int scalars (born SSA) and pin each with a 32-bit
// "+v" asm — asm-defined values cannot be rematerialized; ~210 peak VGPR
// pressure < 256 cap (launch_bounds(512,2)) -> E truly register-resident.

typedef _Float16 h2 __attribute__((ext_vector_type(2)));
typedef _Float16 h8 __attribute__((ext_vector_type(8)));
typedef float f4 __attribute__((ext_vector_type(4)));

#define NB 16
#define NN 2048
#define ND 512
#define NH 4
#define NM 64
#define NITER 30
#define EUSCALE 8.0f   // keeps fp16(eu*EUSCALE) in normal range (eu >= ~1e-5)

static __device__ __forceinline__ float fdot2f(h2 a, h2 b, float c) {
#if __has_builtin(__builtin_amdgcn_fdot2)
  return __builtin_amdgcn_fdot2(a, b, c, false);
#else
  return (float)a[0] * (float)b[0] + (float)a[1] * (float)b[1] + c;
#endif
}

static __device__ __forceinline__ h2 pkrtz(float a, float b) {
  return __builtin_bit_cast(h2, __builtin_amdgcn_cvt_pkrtz(a, b));
}

static __device__ __forceinline__ h8 pack8(float4 a, float4 b) {
  h8 r;
  r[0] = (_Float16)a.x; r[1] = (_Float16)a.y; r[2] = (_Float16)a.z; r[3] = (_Float16)a.w;
  r[4] = (_Float16)b.x; r[5] = (_Float16)b.y; r[6] = (_Float16)b.z; r[7] = (_Float16)b.w;
  return r;
}

static __device__ __forceinline__ float sq4(float4 a) {
  return a.x * a.x + a.y * a.y + a.z * a.z + a.w * a.w;
}

// ---------------------------------------------------------------- k0: x -> xT
__global__ __launch_bounds__(256) void k0_xt(const float* __restrict__ x,
                                             _Float16* __restrict__ xT) {
  __shared__ float tile[64][65];
  const int b = blockIdx.z;
  const int n0 = blockIdx.x * 64;
  const int d0 = blockIdx.y * 64;
  const int t = threadIdx.x;
  const int nr = t >> 2;
  const int ds = (t & 3) * 16;
  const float4* src = (const float4*)(x + ((size_t)(b * NN + n0 + nr) * ND + d0 + ds));
  float4 v0 = src[0], v1 = src[1], v2 = src[2], v3 = src[3];
  float vals[16] = {v0.x, v0.y, v0.z, v0.w, v1.x, v1.y, v1.z, v1.w,
                    v2.x, v2.y, v2.z, v2.w, v3.x, v3.y, v3.z, v3.w};
#pragma unroll
  for (int j = 0; j < 16; ++j) tile[ds + j][nr] = vals[j];
  __syncthreads();
  const int dr = t >> 2;
  const int ns = (t & 3) * 16;
  h8 o0, o1;
#pragma unroll
  for (int j = 0; j < 8; ++j) o0[j] = (_Float16)tile[dr][ns + j];
#pragma unroll
  for (int j = 0; j < 8; ++j) o1[j] = (_Float16)tile[dr][ns + 8 + j];
  _Float16* dst = xT + ((size_t)(b * ND + d0 + dr) * NN + n0 + ns);
  *(h8*)dst = o0;
  *(h8*)(dst + 8) = o1;
}

// ------------------------------------------------------------- k1: build E
__global__ __launch_bounds__(512) void k1_buildE(const float* __restrict__ x,
                                                 const float* __restrict__ w,
                                                 _Float16* __restrict__ E) {
  __shared__ _Float16 Ah[128][72];
  __shared__ _Float16 Bh[256][72];
  __shared__ float x2s[128][4];
  __shared__ float w2s[256][2];
  __shared__ float x2r[128];
  __shared__ float w2r[256];

  const int b = blockIdx.y;
  const int n0 = blockIdx.x * 128;
  const int tid = threadIdx.x;
  const int lane = tid & 63;
  const int wv = tid >> 6;
  const int lrow = lane & 15;
  const int kq = lane >> 4;

  f4 acc[16];
#pragma unroll
  for (int i = 0; i < 16; ++i) acc[i] = (f4){0.f, 0.f, 0.f, 0.f};

  const int ar = tid >> 2, ac = (tid & 3) * 16;
  const int br = tid >> 1, bc = (tid & 1) * 32;
  const float* xsrc = x + ((size_t)(b * NN + n0 + ar) * ND + ac);
  const float* wsrc = w + ((size_t)br * ND + bc);
  float x2p = 0.f, w2p = 0.f;

  for (int kt = 0; kt < 8; ++kt) {
    {
      const float4* s4 = (const float4*)(xsrc + kt * 64);
      float4 a0 = s4[0], a1 = s4[1], a2 = s4[2], a3 = s4[3];
      x2p += sq4(a0) + sq4(a1) + sq4(a2) + sq4(a3);
      *(h8*)&Ah[ar][ac] = pack8(a0, a1);
      *(h8*)&Ah[ar][ac + 8] = pack8(a2, a3);
    }
    {
      const float4* s4 = (const float4*)(wsrc + kt * 64);
      float4 u0 = s4[0], u1 = s4[1], u2 = s4[2], u3 = s4[3];
      float4 u4 = s4[4], u5 = s4[5], u6 = s4[6], u7 = s4[7];
      w2p += sq4(u0) + sq4(u1) + sq4(u2) + sq4(u3)
           + sq4(u4) + sq4(u5) + sq4(u6) + sq4(u7);
      *(h8*)&Bh[br][bc] = pack8(u0, u1);
      *(h8*)&Bh[br][bc + 8] = pack8(u2, u3);
      *(h8*)&Bh[br][bc + 16] = pack8(u4, u5);
      *(h8*)&Bh[br][bc + 24] = pack8(u6, u7);
    }
    __syncthreads();
#pragma unroll
    for (int s = 0; s < 2; ++s) {
      h8 af = *(const h8*)&Ah[wv * 16 + lrow][s * 32 + kq * 8];
#pragma unroll
      for (int cf = 0; cf < 16; ++cf) {
        h8 bf = *(const h8*)&Bh[cf * 16 + lrow][s * 32 + kq * 8];
        acc[cf] = __builtin_amdgcn_mfma_f32_16x16x32_f16(af, bf, acc[cf], 0, 0, 0);
      }
    }
    __syncthreads();
  }

  x2s[ar][tid & 3] = x2p;
  w2s[br][tid & 1] = w2p;
  __syncthreads();
  if (tid < 128) {
    x2r[tid] = x2s[tid][0] + x2s[tid][1] + x2s[tid][2] + x2s[tid][3];
  } else if (tid < 384) {
    const int r = tid - 128;
    w2r[r] = w2s[r][0] + w2s[r][1];
  }
  __syncthreads();

#pragma unroll
  for (int cf = 0; cf < 16; ++cf) {
    const int mg = cf * 16 + lrow;
    const int hh = mg >> 6;
    const int m = mg & 63;
    const float w2v = w2r[mg];
    const float bm = (float)m * (1.0f / 64.0f);
    _Float16* Eb = E + ((size_t)(b * NH + hh) * NN) * NM;
#pragma unroll
    for (int j = 0; j < 4; ++j) {
      const int nl = wv * 16 + kq * 4 + j;
      const int n = n0 + nl;
      const float c2 = x2r[nl] + w2v - 2.0f * acc[cf][j];
      const float Cd = sqrtf(fmaxf(c2, 0.0f));
      const float tt = (float)n * (1.0f / 2048.0f) - bm;
      const float pf = __expf(-100.0f * tt * tt);
      const float Ev = __expf(-10.0f * Cd * pf);
      Eb[(size_t)n * NM + m] = (_Float16)Ev;
    }
  }
}

// ------------------------------------------------------------ k2: Sinkhorn
// One block per (b,h). 512 threads x 4 adjacent rows. E held in 128 NAMED
// u32 SSA scalars, each pinned via 32-bit "+v" asm (remat-proof, compilable).
#define H2C(v, c) __builtin_bit_cast(h2, (v).c)
#define EH(i, j, c) __builtin_bit_cast(h2, E##i##_##j##c)

#define E_LIST(X) \
  X(0,0) X(0,1) X(0,2) X(0,3) X(0,4) X(0,5) X(0,6) X(0,7) \
  X(1,0) X(1,1) X(1,2) X(1,3) X(1,4) X(1,5) X(1,6) X(1,7) \
  X(2,0) X(2,1) X(2,2) X(2,3) X(2,4) X(2,5) X(2,6) X(2,7) \
  X(3,0) X(3,1) X(3,2) X(3,3) X(3,4) X(3,5) X(3,6) X(3,7)

#define TP_LIST(X) \
  X(0,0,x)  X(1,0,y)  X(2,0,z)  X(3,0,w)  X(4,1,x)  X(5,1,y)  X(6,1,z)  X(7,1,w) \
  X(8,2,x)  X(9,2,y)  X(10,2,z) X(11,2,w) X(12,3,x) X(13,3,y) X(14,3,z) X(15,3,w) \
  X(16,4,x) X(17,4,y) X(18,4,z) X(19,4,w) X(20,5,x) X(21,5,y) X(22,5,z) X(23,5,w) \
  X(24,6,x) X(25,6,y) X(26,6,z) X(27,6,w) X(28,7,x) X(29,7,y) X(30,7,z) X(31,7,w)

__global__ __launch_bounds__(512, 2) void k2_sinkhorn(const _Float16* __restrict__ E,
                                                      _Float16* __restrict__ Pt) {
  const int bh = blockIdx.x;
  const int b = bh >> 2, h = bh & 3;
  const int tid = threadIdx.x;
  const int lane = tid & 63;

  __shared__ float evf[64];
  __shared__ __align__(16) h2 evh[32];
  __shared__ unsigned int pbuf[512];

  const _Float16* Ep = E + (size_t)bh * (NN * NM);
  const uint4* s0 = (const uint4*)(Ep + (size_t)(4 * tid + 0) * NM);
  const uint4* s1 = (const uint4*)(Ep + (size_t)(4 * tid + 1) * NM);
  const uint4* s2 = (const uint4*)(Ep + (size_t)(4 * tid + 2) * NM);
  const uint4* s3 = (const uint4*)(Ep + (size_t)(4 * tid + 3) * NM);

  // 128 named u32 scalars = 128 VGPRs of E; born SSA, pinned per-dword.
#define DECLE(i, j) \
  uint4 v##i##_##j = s##i[j]; \
  unsigned int E##i##_##j##x = v##i##_##j.x; \
  unsigned int E##i##_##j##y = v##i##_##j.y; \
  unsigned int E##i##_##j##z = v##i##_##j.z; \
  unsigned int E##i##_##j##w = v##i##_##j.w;
  E_LIST(DECLE)
#undef DECLE
#define PINE(i, j) \
  asm volatile("" : "+v"(E##i##_##j##x), "+v"(E##i##_##j##y), \
                    "+v"(E##i##_##j##z), "+v"(E##i##_##j##w));
  E_LIST(PINE)
#undef PINE

  float eu0 = 1.f, eu1 = 1.f, eu2 = 1.f, eu3 = 1.f;
  if (tid < 64) evf[tid] = 1.f;
  if (tid < 32) evh[tid] = pkrtz(1.f, 1.f);
  __syncthreads();

#pragma unroll 1
  for (int it = 0; it < NITER; ++it) {
    // broadcast ev: 8 named uint4 from LDS (constant indices)
    const uint4* ev4 = (const uint4*)evh;
    uint4 V0 = ev4[0], V1 = ev4[1], V2 = ev4[2], V3 = ev4[3];
    uint4 V4 = ev4[4], V5 = ev4[5], V6 = ev4[6], V7 = ev4[7];

    // u-pass: S[n] = sum_m E*ev ; eu = (1/N)/(eu*S). 8 chains (2/row).
    float a0 = 0.f, b0 = 0.f, a1 = 0.f, b1 = 0.f;
    float a2 = 0.f, b2 = 0.f, a3 = 0.f, b3 = 0.f;
#define UP(i, j, acc) \
    acc = fdot2f(EH(i, j, x), H2C(V##j, x), acc); \
    acc = fdot2f(EH(i, j, y), H2C(V##j, y), acc); \
    acc = fdot2f(EH(i, j, z), H2C(V##j, z), acc); \
    acc = fdot2f(EH(i, j, w), H2C(V##j, w), acc);
    UP(0,0,a0) UP(0,1,a0) UP(0,2,a0) UP(0,3,a0) UP(0,4,b0) UP(0,5,b0) UP(0,6,b0) UP(0,7,b0)
    UP(1,0,a1) UP(1,1,a1) UP(1,2,a1) UP(1,3,a1) UP(1,4,b1) UP(1,5,b1) UP(1,6,b1) UP(1,7,b1)
    UP(2,0,a2) UP(2,1,a2) UP(2,2,a2) UP(2,3,a2) UP(2,4,b2) UP(2,5,b2) UP(2,6,b2) UP(2,7,b2)
    UP(3,0,a3) UP(3,1,a3) UP(3,2,a3) UP(3,3,a3) UP(3,4,b3) UP(3,5,b3) UP(3,6,b3) UP(3,7,b3)
#undef UP
    eu0 = 4.8828125e-4f * __builtin_amdgcn_rcpf(eu0 * (a0 + b0));
    eu1 = 4.8828125e-4f * __builtin_amdgcn_rcpf(eu1 * (a1 + b1));
    eu2 = 4.8828125e-4f * __builtin_amdgcn_rcpf(eu2 * (a2 + b2));
    eu3 = 4.8828125e-4f * __builtin_amdgcn_rcpf(eu3 * (a3 + b3));

    // v-pass local: T'[m] = sum_rows E * (eu*EUSCALE); 32 named h2 partials.
    const h2 p0 = pkrtz(eu0 * EUSCALE, eu0 * EUSCALE);
    const h2 p1 = pkrtz(eu1 * EUSCALE, eu1 * EUSCALE);
    const h2 p2 = pkrtz(eu2 * EUSCALE, eu2 * EUSCALE);
    const h2 p3 = pkrtz(eu3 * EUSCALE, eu3 * EUSCALE);
#define DECLT(q, j, c) \
    h2 t##q = EH(0, j, c) * p0 + EH(1, j, c) * p1 + \
              EH(2, j, c) * p2 + EH(3, j, c) * p3;
    TP_LIST(DECLT)
#undef DECLT

    // register-halving butterfly over named t0..t31: after 5 steps lane l
    // holds the wave-partial for col-pair q = bitrev5(l&31).
    const bool up0 = lane & 1, up1 = (lane >> 1) & 1, up2 = (lane >> 2) & 1;
    const bool up3 = (lane >> 3) & 1, up4 = (lane >> 4) & 1;
#define BF(k, A, B) { \
    h2 keep_ = up##k ? B : A; \
    h2 send_ = up##k ? A : B; \
    int rv_ = __shfl_xor(__builtin_bit_cast(int, send_), 1 << k, 64); \
    A = keep_ + __builtin_bit_cast(h2, rv_); }
    BF(0,t0,t16) BF(0,t1,t17) BF(0,t2,t18)  BF(0,t3,t19)
    BF(0,t4,t20) BF(0,t5,t21) BF(0,t6,t22)  BF(0,t7,t23)
    BF(0,t8,t24) BF(0,t9,t25) BF(0,t10,t26) BF(0,t11,t27)
    BF(0,t12,t28) BF(0,t13,t29) BF(0,t14,t30) BF(0,t15,t31)
    BF(1,t0,t8)  BF(1,t1,t9)  BF(1,t2,t10) BF(1,t3,t11)
    BF(1,t4,t12) BF(1,t5,t13) BF(1,t6,t14) BF(1,t7,t15)
    BF(2,t0,t4)  BF(2,t1,t5)  BF(2,t2,t6)  BF(2,t3,t7)
    BF(3,t0,t2)  BF(3,t1,t3)
    BF(4,t0,t1)
#undef BF
    pbuf[tid] = __builtin_bit_cast(unsigned int, t0);
    __syncthreads();
    if (tid < 32) {
      const int j = tid;
      const int rev = ((j & 1) << 4) | ((j & 2) << 2) | (j & 4) | ((j & 8) >> 2) | ((j & 16) >> 4);
      float T0 = 0.f, T1 = 0.f;
#pragma unroll
      for (int wq = 0; wq < 8; ++wq) {
        h2 a = __builtin_bit_cast(h2, pbuf[wq * 64 + rev]);
        h2 c = __builtin_bit_cast(h2, pbuf[wq * 64 + rev + 32]);
        T0 += (float)a[0] + (float)c[0];
        T1 += (float)a[1] + (float)c[1];
      }
      const float e0 = evf[2 * j], e1 = evf[2 * j + 1];
      const float n0 = EUSCALE * __builtin_amdgcn_rcpf(e0 * T0);
      const float n1 = EUSCALE * __builtin_amdgcn_rcpf(e1 * T1);
      evf[2 * j] = n0;
      evf[2 * j + 1] = n1;
      evh[j] = pkrtz(n0, n1);
    }
    __syncthreads();
  }

  // epilogue: P = E*eu*ev, Pt[b][m][h][n] fp16; rows 4t..4t+3 -> 8B stores.
  _Float16* Pb = Pt + ((size_t)(b * 256 + h)) * NN;
#define EPI(q, j, c) { \
    const float ev0_ = evf[2 * (q)]; \
    const float ev1_ = evf[2 * (q) + 1]; \
    const h2 x0_ = EH(0, j, c), x1_ = EH(1, j, c); \
    const h2 x2_ = EH(2, j, c), x3_ = EH(3, j, c); \
    uint2 st0_, st1_; \
    st0_.x = __builtin_bit_cast(unsigned int, pkrtz((float)x0_[0] * eu0 * ev0_, (float)x1_[0] * eu1 * ev0_)); \
    st0_.y = __builtin_bit_cast(unsigned int, pkrtz((float)x2_[0] * eu2 * ev0_, (float)x3_[0] * eu3 * ev0_)); \
    st1_.x = __builtin_bit_cast(unsigned int, pkrtz((float)x0_[1] * eu0 * ev1_, (float)x1_[1] * eu1 * ev1_)); \
    st1_.y = __builtin_bit_cast(unsigned int, pkrtz((float)x2_[1] * eu2 * ev1_, (float)x3_[1] * eu3 * ev1_)); \
    *(uint2*)(Pb + (size_t)(2 * (q)) * 4 * NN + 4 * tid) = st0_; \
    *(uint2*)(Pb + (size_t)(2 * (q) + 1) * 4 * NN + 4 * tid) = st1_; }
  TP_LIST(EPI)
#undef EPI
}

// ------------------------------------------------------------- k3: out GEMM
__global__ __launch_bounds__(512) void k3_out(const _Float16* __restrict__ Pt,
                                              const _Float16* __restrict__ xT,
                                              float* __restrict__ out) {
  __shared__ _Float16 As[128][72];
  __shared__ _Float16 Bs[64][72];
  const int b = blockIdx.z;
  const int hf = blockIdx.y;
  const int dt = blockIdx.x;
  const int tid = threadIdx.x;
  const int lane = tid & 63;
  const int wv = tid >> 6;
  const int lrow = lane & 15;
  const int kq = lane >> 4;

  f4 acc[4];
#pragma unroll
  for (int i = 0; i < 4; ++i) acc[i] = (f4){0.f, 0.f, 0.f, 0.f};

  const int ar = tid >> 2, ac = (tid & 3) * 16;
  const int brd = tid >> 3, bn = (tid & 7) * 8;
  const _Float16* asrc = Pt + ((size_t)(b * 256 + hf * 128 + ar) * NN + ac);
  const _Float16* bsrc = xT + ((size_t)(b * ND + dt * 64 + brd) * NN + bn);

  for (int kt = 0; kt < 32; ++kt) {
    const int k0 = kt * 64;
    h8 a0 = *(const h8*)(asrc + k0);
    h8 a1 = *(const h8*)(asrc + k0 + 8);
    h8 bv = *(const h8*)(bsrc + k0);
    *(h8*)&As[ar][ac] = a0;
    *(h8*)&As[ar][ac + 8] = a1;
    *(h8*)&Bs[brd][bn] = bv;
    __syncthreads();
#pragma unroll
    for (int s = 0; s < 2; ++s) {
      h8 af = *(const h8*)&As[wv * 16 + lrow][s * 32 + kq * 8];
#pragma unroll
      for (int cf = 0; cf < 4; ++cf) {
        h8 bf = *(const h8*)&Bs[cf * 16 + lrow][s * 32 + kq * 8];
        acc[cf] = __builtin_amdgcn_mfma_f32_16x16x32_f16(af, bf, acc[cf], 0, 0, 0);
      }
    }
    __syncthreads();
  }
#pragma unroll
  for (int cf = 0; cf < 4; ++cf) {
    const int d = dt * 64 + cf * 16 + lrow;
#pragma unroll
    for (int j = 0; j < 4; ++j) {
      const int row = hf * 128 + wv * 16 + kq * 4 + j;
      out[(size_t)(b * 256 + row) * ND + d] = acc[cf][j];
    }
  }
}

// ---------------------------------------------------------------- launcher
extern "C" void kernel_launch(void* const* d_in, const int* in_sizes, int n_in,
                              void* d_out, int out_size, void* d_ws, size_t ws_size,
                              hipStream_t stream) {
  const float* x = (const float*)d_in[0];
  const float* w = (const float*)d_in[1];
  float* out = (float*)d_out;
  char* ws = (char*)d_ws;
  _Float16* xT = (_Float16*)ws;
  _Float16* E  = (_Float16*)(ws + (size_t)33554432);
  _Float16* Pt = (_Float16*)(ws + (size_t)50331648);

  k0_xt<<<dim3(32, 8, NB), 256, 0, stream>>>(x, xT);
  k1_buildE<<<dim3(16, NB), 512, 0, stream>>>(x, w, E);
  k2_sinkhorn<<<dim3(64), 512, 0, stream>>>(E, Pt);
  k3_out<<<dim3(8, 2, NB), 512, 0, stream>>>(Pt, xT, out);
}